// Round 9
// baseline (89.266 us; speedup 1.0000x reference)
//
#include <hip/hip_runtime.h>
#include <stdint.h>

// rotate-left via v_alignbit_b32 (1 instruction)
__device__ __forceinline__ uint32_t rotl(uint32_t v, int r) {
  return __builtin_amdgcn_alignbit(v, v, (uint32_t)(32 - r));
}

// ---------------- Threefry-2x32, 20 rounds (host key derivation) ----------
__host__ inline void tf2x32(uint32_t k0, uint32_t k1, uint32_t x0, uint32_t x1,
                            uint32_t& o0, uint32_t& o1) {
  uint32_t k2 = k0 ^ k1 ^ 0x1BD11BDAu;
#define TFR(r) { x0 += x1; x1 = (x1 << (r)) | (x1 >> (32 - (r))); x1 ^= x0; }
  x0 += k0; x1 += k1;
  TFR(13) TFR(15) TFR(26) TFR(6)  x0 += k1; x1 += k2 + 1u;
  TFR(17) TFR(29) TFR(16) TFR(24) x0 += k2; x1 += k0 + 2u;
  TFR(13) TFR(15) TFR(26) TFR(6)  x0 += k0; x1 += k1 + 3u;
  TFR(17) TFR(29) TFR(16) TFR(24) x0 += k1; x1 += k2 + 4u;
  TFR(13) TFR(15) TFR(26) TFR(6)  x0 += k2; x1 += k0 + 5u;
#undef TFR
  o0 = x0; o1 = x1;
}

// 4-chain lockstep threefry at counters (0, jb + STRIDE*i); out = o0^o1
// (JAX partitionable random_bits). Key injections fused into following
// round's add (v_add3), round-1 add merged into init.
template <unsigned STRIDE>
__device__ __forceinline__ void tf4(uint32_t k0, uint32_t k1, uint32_t jb,
                                    uint32_t out[4]) {
  uint32_t k2 = k0 ^ k1 ^ 0x1BD11BDAu;
  uint32_t k21 = k2 + 1u, k02 = k0 + 2u, k13 = k1 + 3u, k24 = k2 + 4u,
           k05 = k0 + 5u;
  uint32_t a[4], b[4];
  uint32_t jk = jb + k1;
#pragma unroll
  for (int i = 0; i < 4; ++i) {
    b[i] = jk + STRIDE * (unsigned)i;
    a[i] = k0 + b[i];                   // round-1 "a += b" merged with a = k0
  }
#pragma unroll
  for (int i = 0; i < 4; ++i) b[i] = rotl(b[i], 13) ^ a[i];  // round-1 tail
#define RND4(r)                                                        \
  _Pragma("unroll") for (int i = 0; i < 4; ++i) {                      \
    a[i] += b[i];                                                      \
    b[i] = rotl(b[i], (r)) ^ a[i];                                     \
  }
#define RNDI4(r, ka, kbn)                                              \
  _Pragma("unroll") for (int i = 0; i < 4; ++i) {                      \
    b[i] += (kbn);                                                     \
    a[i] = a[i] + (ka) + b[i];  /* v_add3_u32 */                       \
    b[i] = rotl(b[i], (r)) ^ a[i];                                     \
  }
  RND4(15) RND4(26) RND4(6)
  RNDI4(17, k1, k21) RND4(29) RND4(16) RND4(24)
  RNDI4(13, k2, k02) RND4(15) RND4(26) RND4(6)
  RNDI4(17, k0, k13) RND4(29) RND4(16) RND4(24)
  RNDI4(13, k1, k24) RND4(15) RND4(26) RND4(6)
#undef RND4
#undef RNDI4
#pragma unroll
  for (int i = 0; i < 4; ++i) out[i] = (a[i] + k2) ^ (b[i] + k05);
}

// bits -> float in [0,1): (bits>>9)|0x3F800000 bitcast - 1.0 (JAX _uniform)
__device__ __forceinline__ float bits_to_f01(uint32_t b) {
  return __uint_as_float((b >> 9) | 0x3F800000u) - 1.0f;
}

// order-preserving float<->uint encode for atomicMin on floats
__device__ __forceinline__ unsigned encf(float f) {
  unsigned u = __float_as_uint(f);
  return (u & 0x80000000u) ? ~u : (u | 0x80000000u);
}
__device__ __forceinline__ float decf(unsigned u) {
  unsigned b = (u & 0x80000000u) ? (u & 0x7FFFFFFFu) : ~u;
  return __uint_as_float(b);
}

struct TP {
  const float* x;
  float* out;
  const int* midx;
  uint32_t uk0, uk1, nk0, nk1;
  unsigned k;       // N = 25 << k
  unsigned N;
  unsigned tot;     // 680 * N
  unsigned cbase;   // first chunk id (1024 elems/chunk)
  unsigned cend;    // one past last chunk id
};

#define NGRID 1008u
#define PREPB 263u
#define SPIN_TGT 262u   // 0xFFFFFFFF + 263 (mod 2^32)

// process one 1024-elem chunk starting at element s of tensor P (4/thread)
__device__ __forceinline__ void process_chunk(
    const TP& P, unsigned t, unsigned s, unsigned tid,
    const unsigned* mins, float sv, float lo) {
  unsigned i0 = s + tid * 4u;
  if (i0 >= P.tot) return;

  unsigned bc = __umulhi(i0 >> P.k, 0x51EB851Fu) >> 3;  // (i0/2^k)/25
  unsigned n0 = i0 - bc * P.N;       // 4 consecutive n, same (b,c)
  unsigned b = (bc * 772u) >> 16;    // exact for bc < 680
  unsigned c = bc - b * 85u;

  float4 va = *reinterpret_cast<const float4*>(P.x + i0);

  // ---- noise bits: 4 lockstep threefry chains ----
  unsigned jb = (b * P.N + n0) * 85u + c;  // noise array [B,N,C] flat index
  uint32_t nb[4];
  tf4<85u>(P.nk0, P.nk1, jb, nb);

  // ---- zlite, coefficient-major; 3-term central + linear tail ----
  float x4[4], L4[4], t4[4], p4[4], nz[4];
#pragma unroll
  for (int q = 0; q < 4; ++q) {
    float f = __uint_as_float((nb[q] >> 9) | 0x3F800000u) - 1.0f;
    x4[q] = fmaxf(lo, fmaf(f, 2.0f, lo));
  }
#pragma unroll
  for (int q = 0; q < 4; ++q) L4[q] = __log2f(fmaf(-x4[q], x4[q], 1.0f));
#pragma unroll
  for (int q = 0; q < 4; ++q) t4[q] = fmaf(L4[q], -0.69314718f, -2.5f);
#pragma unroll
  for (int q = 0; q < 4; ++q) p4[q] = fmaf(-0.00417768164f, t4[q], 0.246640727f);
#pragma unroll
  for (int q = 0; q < 4; ++q) p4[q] = fmaf(p4[q], t4[q], 1.50140941f);
#pragma unroll
  for (int q = 0; q < 4; ++q) {
    float pt = fmaf(L4[q], -0.1113356f, 1.327237f);   // tail (w>=5)
    p4[q] = (L4[q] > -7.2134752f) ? p4[q] : pt;
    nz[q] = p4[q] * x4[q];
  }

  float vv[4] = {va.x, va.y, va.z, va.w};

  // ---- class scatter-replace (batch 0, channels 5..84) ----
  if (b == 0u && c >= 5u) {
    unsigned kk = c - 5u;
    int4 ma = *reinterpret_cast<const int4*>(P.midx + n0);
    float clsmin = decf(mins[t]);
    uint32_t ub[4];
    tf4<80u>(P.uk0, P.uk1, n0 * 80u + kk, ub);   // uniform array [N,80]
    int mm[4] = {ma.x, ma.y, ma.z, ma.w};
#pragma unroll
    for (int q = 0; q < 4; ++q) {
      if ((unsigned)mm[q] != kk) vv[q] = bits_to_f01(ub[q]) * clsmin;
    }
  }

#pragma unroll
  for (int q = 0; q < 4; ++q) vv[q] = fmaf(nz[q], sv, vv[q]);
  *reinterpret_cast<float4*>(P.out + i0) = make_float4(vv[0], vv[1], vv[2], vv[3]);
}

// ---------------- single fused kernel: prep + barrier + main ---------------
// Grid = 1008 blocks, __launch_bounds__(256,4) => <=128 VGPR => 4 blocks/CU
// => all 1008 co-resident => the done-counter barrier cannot deadlock.
__global__ __launch_bounds__(256, 4) void fused_all(
    TP p0, TP p1, TP p2, unsigned* __restrict__ minsdone,
    const float* __restrict__ valuep) {
  const unsigned bid = blockIdx.x, tid = threadIdx.x;
  unsigned* mins = minsdone;        // [0..2], init 0xFFFFFFFF
  unsigned* done = minsdone + 3;    // init 0xFFFFFFFF; 263 adds -> 262

  // ---------- prep phase (blocks 0..262): argmax + min of batch-0 classes --
  if (bid < PREPB) {
    const float* x; int* midx; unsigned* mE; unsigned N; unsigned lb;
    if (bid < 200u)      { x = p0.x; midx = (int*)p0.midx; mE = mins;     N = 25600u; lb = bid; }
    else if (bid < 250u) { x = p1.x; midx = (int*)p1.midx; mE = mins + 1; N = 6400u;  lb = bid - 200u; }
    else                 { x = p2.x; midx = (int*)p2.midx; mE = mins + 2; N = 1600u;  lb = bid - 250u; }
    unsigned p = lb * 128u + (tid >> 1);
    unsigned h = tid & 1u;           // half: channels 40h .. 40h+39
    float best = -INFINITY, mn = INFINITY;
    int bi = 0;
    if (p < N) {
      const float* pp = x + (5u + 40u * h) * N + p;
#pragma unroll 8
      for (int k = 0; k < 40; ++k) {
        float v = pp[(unsigned)k * N];
        if (v > best) { best = v; bi = (int)(40u * h) + k; }  // '>': first max
        mn = fminf(mn, v);
      }
    }
    float ob = __shfl_xor(best, 1, 64);
    int obi = __shfl_xor(bi, 1, 64);
    float omn = __shfl_xor(mn, 1, 64);
    float bE = (h == 0u) ? best : ob;  int iE = (h == 0u) ? bi : obi;
    float bO = (h == 0u) ? ob : best;  int iO = (h == 0u) ? obi : bi;
    int mbi = (bO > bE) ? iO : iE;     // ties -> lower-k half (first max)
    mn = fminf(mn, omn);
    if (h == 0u && p < N) midx[p] = mbi;
    unsigned u = encf(mn);
    for (int off = 32; off > 0; off >>= 1) {
      unsigned o = __shfl_down(u, (unsigned)off, 64);
      u = (o < u) ? o : u;
    }
    if ((tid & 63u) == 0u) atomicMin(mE, u);
    __syncthreads();   // drains all this block's stores (vmcnt 0 before barrier)
    if (tid == 0)
      __hip_atomic_fetch_add(done, 1u, __ATOMIC_RELEASE, __HIP_MEMORY_SCOPE_AGENT);
  }

  float value = *valuep;
  float sv = value * 1.41421356237309515f;
  const float lo = __uint_as_float(0xBF7FFFFFu);  // nextafter(-1.f, 0.f)
  const unsigned TC = p2.cend;

  // ---------- pass 1: chunks with no batch-0 class elements ----------------
  for (unsigned w = bid; w < TC; w += NGRID) {
    TP P = p0; unsigned t = 0u;
    if (w >= p1.cbase) { P = p1; t = 1u; }
    if (w >= p2.cbase) { P = p2; t = 2u; }
    unsigned s = (w - P.cbase) << 10;
    unsigned e = min(s + 1020u, P.tot - 4u);
    unsigned bcs = __umulhi(s >> P.k, 0x51EB851Fu) >> 3;
    unsigned bce = __umulhi(e >> P.k, 0x51EB851Fu) >> 3;
    if ((bcs < 85u) && (bce >= 5u)) continue;   // class-involved: defer
    process_chunk(P, t, s, tid, mins, sv, lo);
  }

  // ---------- barrier: wait until all 263 prep blocks have published -------
  while (__hip_atomic_load(done, __ATOMIC_ACQUIRE, __HIP_MEMORY_SCOPE_AGENT)
         != SPIN_TGT) {}

  // ---------- pass 2: class-involved chunks --------------------------------
  for (unsigned w = bid; w < TC; w += NGRID) {
    TP P = p0; unsigned t = 0u;
    if (w >= p1.cbase) { P = p1; t = 1u; }
    if (w >= p2.cbase) { P = p2; t = 2u; }
    unsigned s = (w - P.cbase) << 10;
    unsigned e = min(s + 1020u, P.tot - 4u);
    unsigned bcs = __umulhi(s >> P.k, 0x51EB851Fu) >> 3;
    unsigned bce = __umulhi(e >> P.k, 0x51EB851Fu) >> 3;
    if (!((bcs < 85u) && (bce >= 5u))) continue;
    process_chunk(P, t, s, tid, mins, sv, lo);
  }
}

extern "C" void kernel_launch(void* const* d_in, const int* in_sizes, int n_in,
                              void* d_out, int out_size, void* d_ws, size_t ws_size,
                              hipStream_t stream) {
  const float* xs[3] = {(const float*)d_in[0], (const float*)d_in[1], (const float*)d_in[2]};
  const float* valuep = (const float*)d_in[3];
  float* out = (float*)d_out;

  const unsigned Ns[3] = {25600u, 6400u, 1600u};
  const unsigned ks[3] = {10u, 8u, 6u};   // N = 25 << k

  // workspace: midx0 | midx1 | midx2 | [mins0, mins1, mins2, done]
  int* midx[3];
  midx[0] = (int*)d_ws;
  midx[1] = midx[0] + Ns[0];
  midx[2] = midx[1] + Ns[1];
  unsigned* minsdone = (unsigned*)(midx[2] + Ns[2]);
  hipMemsetAsync(minsdone, 0xFF, 4 * sizeof(unsigned), stream);

  // Host-side key derivation (partitionable threefry):
  //   base = key(42) = (0,42); key_i = threefry(base,(0,i));
  //   split(key_i) -> k1 = threefry(key_i,(0,0)) [uniform], k2 = threefry(key_i,(0,1)) [normal]
  TP p[3];
  unsigned chunk_acc = 0;
  float* outp = out;
  for (int i = 0; i < 3; ++i) {
    uint32_t f0, f1;
    tf2x32(0u, 42u, 0u, (uint32_t)i, f0, f1);
    tf2x32(f0, f1, 0u, 0u, p[i].uk0, p[i].uk1);
    tf2x32(f0, f1, 0u, 1u, p[i].nk0, p[i].nk1);
    p[i].x = xs[i];
    p[i].out = outp;
    p[i].midx = midx[i];
    p[i].k = ks[i];
    p[i].N = Ns[i];
    p[i].tot = 680u * Ns[i];
    p[i].cbase = chunk_acc;
    chunk_acc += (p[i].tot + 1023u) / 1024u;   // 1024 elems per chunk
    p[i].cend = chunk_acc;
    outp += (size_t)680 * Ns[i];
  }

  fused_all<<<NGRID, 256, 0, stream>>>(p[0], p[1], p[2], minsdone, valuep);
}

// Round 10
// 63.931 us; speedup vs baseline: 1.3963x; 1.3963x over previous
//
#include <hip/hip_runtime.h>
#include <stdint.h>

// rotate-left via v_alignbit_b32 (1 instruction)
__device__ __forceinline__ uint32_t rotl(uint32_t v, int r) {
  return __builtin_amdgcn_alignbit(v, v, (uint32_t)(32 - r));
}

// ---------------- Threefry-2x32, 20 rounds (host key derivation) ----------
__host__ inline void tf2x32(uint32_t k0, uint32_t k1, uint32_t x0, uint32_t x1,
                            uint32_t& o0, uint32_t& o1) {
  uint32_t k2 = k0 ^ k1 ^ 0x1BD11BDAu;
#define TFR(r) { x0 += x1; x1 = (x1 << (r)) | (x1 >> (32 - (r))); x1 ^= x0; }
  x0 += k0; x1 += k1;
  TFR(13) TFR(15) TFR(26) TFR(6)  x0 += k1; x1 += k2 + 1u;
  TFR(17) TFR(29) TFR(16) TFR(24) x0 += k2; x1 += k0 + 2u;
  TFR(13) TFR(15) TFR(26) TFR(6)  x0 += k0; x1 += k1 + 3u;
  TFR(17) TFR(29) TFR(16) TFR(24) x0 += k1; x1 += k2 + 4u;
  TFR(13) TFR(15) TFR(26) TFR(6)  x0 += k2; x1 += k0 + 5u;
#undef TFR
  o0 = x0; o1 = x1;
}

// 4-chain lockstep threefry at counters (0, jb + STRIDE*i); out = o0^o1
// (JAX partitionable random_bits). Key injections fused into following
// round's add (v_add3), round-1 add merged into init.
template <unsigned STRIDE>
__device__ __forceinline__ void tf4(uint32_t k0, uint32_t k1, uint32_t jb,
                                    uint32_t out[4]) {
  uint32_t k2 = k0 ^ k1 ^ 0x1BD11BDAu;
  uint32_t k21 = k2 + 1u, k02 = k0 + 2u, k13 = k1 + 3u, k24 = k2 + 4u,
           k05 = k0 + 5u;
  uint32_t a[4], b[4];
  uint32_t jk = jb + k1;
#pragma unroll
  for (int i = 0; i < 4; ++i) {
    b[i] = jk + STRIDE * (unsigned)i;
    a[i] = k0 + b[i];                   // round-1 "a += b" merged with a = k0
  }
#pragma unroll
  for (int i = 0; i < 4; ++i) b[i] = rotl(b[i], 13) ^ a[i];  // round-1 tail
#define RND4(r)                                                        \
  _Pragma("unroll") for (int i = 0; i < 4; ++i) {                      \
    a[i] += b[i];                                                      \
    b[i] = rotl(b[i], (r)) ^ a[i];                                     \
  }
#define RNDI4(r, ka, kbn)                                              \
  _Pragma("unroll") for (int i = 0; i < 4; ++i) {                      \
    b[i] += (kbn);                                                     \
    a[i] = a[i] + (ka) + b[i];  /* v_add3_u32 */                       \
    b[i] = rotl(b[i], (r)) ^ a[i];                                     \
  }
  RND4(15) RND4(26) RND4(6)
  RNDI4(17, k1, k21) RND4(29) RND4(16) RND4(24)
  RNDI4(13, k2, k02) RND4(15) RND4(26) RND4(6)
  RNDI4(17, k0, k13) RND4(29) RND4(16) RND4(24)
  RNDI4(13, k1, k24) RND4(15) RND4(26) RND4(6)
#undef RND4
#undef RNDI4
#pragma unroll
  for (int i = 0; i < 4; ++i) out[i] = (a[i] + k2) ^ (b[i] + k05);
}

// bits -> float in [0,1): (bits>>9)|0x3F800000 bitcast - 1.0 (JAX _uniform)
__device__ __forceinline__ float bits_to_f01(uint32_t b) {
  return __uint_as_float((b >> 9) | 0x3F800000u) - 1.0f;
}

// order-preserving float<->uint encode for min on floats
__device__ __forceinline__ unsigned encf(float f) {
  unsigned u = __float_as_uint(f);
  return (u & 0x80000000u) ? ~u : (u | 0x80000000u);
}
__device__ __forceinline__ float decf(unsigned u) {
  unsigned b = (u & 0x80000000u) ? (u & 0x7FFFFFFFu) : ~u;
  return __uint_as_float(b);
}

struct TP {
  const float* x;
  float* out;
  int* midx;
  uint32_t uk0, uk1, nk0, nk1;
  unsigned k;         // N = 25 << k
  unsigned N;
  unsigned tot;       // 680 * N
  unsigned lo_cnt;    // nonclass chunks below class region
  unsigned hi_start;  // first chunk after class region
  unsigned nc_base, nc_end;    // prefix range of nonclass chunks (kernel A)
  unsigned cls_lo;             // first class-involved chunk
  unsigned cls_base, cls_end;  // prefix range of class chunks (kernel B)
  unsigned slot_base, slot_cnt;  // per-block min slots of this tensor
};

#define PREPB 263u

// process one 1024-elem chunk starting at element s of tensor P (4/thread)
template <bool CLS>
__device__ __forceinline__ void process_chunk(
    const TP& P, unsigned s, unsigned tid, float clsmin, float sv, float lo) {
  unsigned i0 = s + tid * 4u;
  if (i0 >= P.tot) return;

  unsigned bc = __umulhi(i0 >> P.k, 0x51EB851Fu) >> 3;  // (i0/2^k)/25
  unsigned n0 = i0 - bc * P.N;       // 4 consecutive n, same (b,c)
  unsigned b = (bc * 772u) >> 16;    // exact for bc < 680
  unsigned c = bc - b * 85u;

  float4 va = *reinterpret_cast<const float4*>(P.x + i0);

  // ---- noise bits: 4 lockstep threefry chains ----
  unsigned jb = (b * P.N + n0) * 85u + c;  // noise array [B,N,C] flat index
  uint32_t nb[4];
  tf4<85u>(P.nk0, P.nk1, jb, nb);

  // ---- zlite, coefficient-major; 3-term central + linear tail ----
  float x4[4], L4[4], t4[4], p4[4], nz[4];
#pragma unroll
  for (int q = 0; q < 4; ++q) {
    float f = __uint_as_float((nb[q] >> 9) | 0x3F800000u) - 1.0f;
    x4[q] = fmaf(f, 2.0f, lo);   // stays in [lo, 1): fmax redundant
  }
#pragma unroll
  for (int q = 0; q < 4; ++q) L4[q] = __log2f(fmaf(-x4[q], x4[q], 1.0f));
#pragma unroll
  for (int q = 0; q < 4; ++q) t4[q] = fmaf(L4[q], -0.69314718f, -2.5f);
#pragma unroll
  for (int q = 0; q < 4; ++q) p4[q] = fmaf(-0.00417768164f, t4[q], 0.246640727f);
#pragma unroll
  for (int q = 0; q < 4; ++q) p4[q] = fmaf(p4[q], t4[q], 1.50140941f);
#pragma unroll
  for (int q = 0; q < 4; ++q) {
    float pt = fmaf(L4[q], -0.1113356f, 1.327237f);   // tail (w>=5)
    p4[q] = (L4[q] > -7.2134752f) ? p4[q] : pt;
    nz[q] = p4[q] * x4[q];
  }

  float vv[4] = {va.x, va.y, va.z, va.w};

  if (CLS) {
    // ---- class scatter-replace (batch 0, channels 5..84) ----
    if (b == 0u && c >= 5u) {
      unsigned kk = c - 5u;
      int4 ma = *reinterpret_cast<const int4*>(P.midx + n0);
      uint32_t ub[4];
      tf4<80u>(P.uk0, P.uk1, n0 * 80u + kk, ub);   // uniform array [N,80]
      int mm[4] = {ma.x, ma.y, ma.z, ma.w};
#pragma unroll
      for (int q = 0; q < 4; ++q) {
        if ((unsigned)mm[q] != kk) vv[q] = bits_to_f01(ub[q]) * clsmin;
      }
    }
  }

#pragma unroll
  for (int q = 0; q < 4; ++q) vv[q] = fmaf(nz[q], sv, vv[q]);
  *reinterpret_cast<float4*>(P.out + i0) = make_float4(vv[0], vv[1], vv[2], vv[3]);
}

// ---------------- kernel A: prep blocks + nonclass-chunk blocks ------------
// Blocks 0..262 compute argmax/min (write midx + slot[bid]; no reader in A).
// Blocks 263.. process chunks with NO batch-0 class elements.
__global__ __launch_bounds__(256) void kA(
    TP p0, TP p1, TP p2, unsigned* __restrict__ slots,
    const float* __restrict__ valuep) {
  const unsigned bid = blockIdx.x, tid = threadIdx.x;

  if (bid < PREPB) {
    // ---------- prep: per-pixel argmax + per-block min ----------
    const float* x; int* midx; unsigned N; unsigned lb;
    if (bid < 200u)      { x = p0.x; midx = p0.midx; N = 25600u; lb = bid; }
    else if (bid < 250u) { x = p1.x; midx = p1.midx; N = 6400u;  lb = bid - 200u; }
    else                 { x = p2.x; midx = p2.midx; N = 1600u;  lb = bid - 250u; }
    unsigned p = lb * 128u + (tid >> 1);
    unsigned h = tid & 1u;           // half: channels 40h .. 40h+39
    float best = -INFINITY, mn = INFINITY;
    int bi = 0;
    if (p < N) {
      const float* pp = x + (5u + 40u * h) * N + p;
#pragma unroll 8
      for (int k = 0; k < 40; ++k) {
        float v = pp[(unsigned)k * N];
        if (v > best) { best = v; bi = (int)(40u * h) + k; }  // '>': first max
        mn = fminf(mn, v);
      }
    }
    float ob = __shfl_xor(best, 1, 64);
    int obi = __shfl_xor(bi, 1, 64);
    float omn = __shfl_xor(mn, 1, 64);
    float bE = (h == 0u) ? best : ob;  int iE = (h == 0u) ? bi : obi;
    float bO = (h == 0u) ? ob : best;  int iO = (h == 0u) ? obi : bi;
    int mbi = (bO > bE) ? iO : iE;     // ties -> lower-k half (first max)
    mn = fminf(mn, omn);
    if (h == 0u && p < N) midx[p] = mbi;
    unsigned u = encf(mn);
    for (int off = 32; off > 0; off >>= 1) {
      unsigned o = __shfl_down(u, (unsigned)off, 64);
      u = (o < u) ? o : u;
    }
    __shared__ unsigned ls[4];
    if ((tid & 63u) == 0u) ls[tid >> 6] = u;
    __syncthreads();
    if (tid == 0u) {
      unsigned m = min(min(ls[0], ls[1]), min(ls[2], ls[3]));
      slots[bid] = m;   // plain store: no init, no atomics
    }
    return;
  }

  unsigned w = bid - PREPB;
  TP P = p0;
  if (w >= p0.nc_end) P = p1;
  if (w >= p1.nc_end) P = p2;
  unsigned local = w - P.nc_base;
  unsigned chunk = (local < P.lo_cnt) ? local : P.hi_start + (local - P.lo_cnt);

  float value = *valuep;
  float sv = value * 1.41421356237309515f;
  const float lo = __uint_as_float(0xBF7FFFFFu);  // nextafter(-1.f, 0.f)
  process_chunk<false>(P, chunk << 10, tid, 0.0f, sv, lo);
}

// ---------------- kernel B: class-involved chunks (after prep) -------------
__global__ __launch_bounds__(256) void kB(
    TP p0, TP p1, TP p2, const unsigned* __restrict__ slots,
    const float* __restrict__ valuep) {
  const unsigned bid = blockIdx.x, tid = threadIdx.x;
  TP P = p0;
  if (bid >= p0.cls_end) P = p1;
  if (bid >= p1.cls_end) P = p2;
  unsigned chunk = P.cls_lo + (bid - P.cls_base);

  // reduce this tensor's per-block min slots (slot_cnt <= 200 < 256)
  __shared__ unsigned ls[4];
  unsigned u = (tid < P.slot_cnt) ? slots[P.slot_base + tid] : 0xFFFFFFFFu;
  for (int off = 32; off > 0; off >>= 1) {
    unsigned o = __shfl_down(u, (unsigned)off, 64);
    u = (o < u) ? o : u;
  }
  if ((tid & 63u) == 0u) ls[tid >> 6] = u;
  __syncthreads();
  float clsmin = decf(min(min(ls[0], ls[1]), min(ls[2], ls[3])));

  float value = *valuep;
  float sv = value * 1.41421356237309515f;
  const float lo = __uint_as_float(0xBF7FFFFFu);
  process_chunk<true>(P, chunk << 10, tid, clsmin, sv, lo);
}

extern "C" void kernel_launch(void* const* d_in, const int* in_sizes, int n_in,
                              void* d_out, int out_size, void* d_ws, size_t ws_size,
                              hipStream_t stream) {
  const float* xs[3] = {(const float*)d_in[0], (const float*)d_in[1], (const float*)d_in[2]};
  const float* valuep = (const float*)d_in[3];
  float* out = (float*)d_out;

  const unsigned Ns[3] = {25600u, 6400u, 1600u};
  const unsigned ks[3] = {10u, 8u, 6u};   // N = 25 << k
  const unsigned slot_base[3] = {0u, 200u, 250u};
  const unsigned slot_cnt[3] = {200u, 50u, 13u};

  // workspace: midx0 | midx1 | midx2 | slots[263]
  int* midx[3];
  midx[0] = (int*)d_ws;
  midx[1] = midx[0] + Ns[0];
  midx[2] = midx[1] + Ns[1];
  unsigned* slots = (unsigned*)(midx[2] + Ns[2]);

  // Host-side key derivation (partitionable threefry):
  //   base = key(42) = (0,42); key_i = threefry(base,(0,i));
  //   split(key_i) -> k1 = threefry(key_i,(0,0)) [uniform], k2 = threefry(key_i,(0,1)) [normal]
  TP p[3];
  unsigned nc_acc = 0, cls_acc = 0;
  float* outp = out;
  for (int i = 0; i < 3; ++i) {
    uint32_t f0, f1;
    tf2x32(0u, 42u, 0u, (uint32_t)i, f0, f1);
    tf2x32(f0, f1, 0u, 0u, p[i].uk0, p[i].uk1);
    tf2x32(f0, f1, 0u, 1u, p[i].nk0, p[i].nk1);
    const unsigned N = Ns[i];
    p[i].x = xs[i];
    p[i].out = outp;
    p[i].midx = midx[i];
    p[i].k = ks[i];
    p[i].N = N;
    p[i].tot = 680u * N;
    const unsigned chunks = (p[i].tot + 1023u) / 1024u;
    const unsigned cls_lo = (5u * N) >> 10;              // first chunk w/ class
    const unsigned cls_hi = (85u * N - 1u) >> 10;        // last chunk w/ class
    p[i].cls_lo = cls_lo;
    p[i].lo_cnt = cls_lo;
    p[i].hi_start = cls_hi + 1u;
    const unsigned nc_cnt = cls_lo + (chunks - (cls_hi + 1u));
    const unsigned cls_cnt = cls_hi - cls_lo + 1u;
    p[i].nc_base = nc_acc;  nc_acc += nc_cnt;   p[i].nc_end = nc_acc;
    p[i].cls_base = cls_acc; cls_acc += cls_cnt; p[i].cls_end = cls_acc;
    p[i].slot_base = slot_base[i];
    p[i].slot_cnt = slot_cnt[i];
    outp += (size_t)680 * N;
  }

  kA<<<PREPB + nc_acc, 256, 0, stream>>>(p[0], p[1], p[2], slots, valuep);
  kB<<<cls_acc, 256, 0, stream>>>(p[0], p[1], p[2], slots, valuep);
}